// Round 2
// baseline (366.150 us; speedup 1.0000x reference)
//
#include <hip/hip_runtime.h>
#include <math.h>

#define BB 1024
#define TT 512
#define CC 53
#define BOS 1
#define EOS 2

__device__ __forceinline__ float bcast_lane(float x, int l) {
    return __uint_as_float(__builtin_amdgcn_readlane(__float_as_uint(x), l));
}

__global__ __launch_bounds__(64) void crf_batch_kernel(
    const float* __restrict__ em,     // B,T,C
    const int*   __restrict__ tags,   // B,T
    const float* __restrict__ mask,   // B,T
    const float* __restrict__ trans,  // C,C
    float*       __restrict__ partial) // B  (partition - score)
{
    const int b = blockIdx.x;
    const int lane = threadIdx.x;             // 0..63
    const int cc = lane < CC ? lane : CC - 1; // lanes >= C mirror lane 52

    // ---- length = sum(mask[b,:]) (exact: entries are 0.0/1.0) ----
    const float* mrow = mask + (size_t)b * TT;
    float msum = 0.f;
    #pragma unroll
    for (int i = 0; i < TT / 64; ++i) msum += mrow[lane + 64 * i];
    #pragma unroll
    for (int o = 32; o > 0; o >>= 1) msum += __shfl_xor(msum, o);
    const int len = (int)(msum + 0.5f);       // in [256, 511]

    // ---- score (gather part), lane-parallel over t ----
    const int* trow = tags + (size_t)b * TT;
    const float* ep = em + (size_t)b * TT * CC;
    float sc = 0.f;
    for (int t = 2 + lane; t < len; t += 64) {
        int tg = trow[t];
        int tp = trow[t - 1];
        sc += ep[(size_t)t * CC + tg] + trans[tp * CC + tg];
    }
    #pragma unroll
    for (int o = 32; o > 0; o >>= 1) sc += __shfl_xor(sc, o);
    if (lane == 0) {
        int t1 = trow[1];
        sc += trans[BOS * CC + t1] + ep[1 * CC + t1];   // "first"
        int tl = trow[len];
        sc += trans[tl * CC + EOS];                      // "last" (ref indexes tags[:,len])
    }

    // ---- W[c'][lane] = exp(trans[c', lane]) in registers ----
    float w[CC];
    #pragma unroll
    for (int i = 0; i < CC; ++i) w[i] = __expf(trans[i * CC + cc]);

    // ---- linear-domain forward: u = exp(alpha), kexp = accumulated pow2 scale ----
    float u = __expf(trans[BOS * CC + cc] + ep[1 * CC + cc]);  // |alpha1| small, safe
    int kexp = 0;

    // 3-deep prefetch of pe[t] = exp(em[t, cc])
    float pe0 = __expf(ep[2 * CC + cc]);
    float pe1 = __expf(ep[3 * CC + cc]);
    float pe2 = __expf(ep[4 * CC + cc]);

    for (int t = 2; t < len; ++t) {
        // ---- off-critical-path renorm: k = exponent of u[lane0]; fold 2^-k into pe ----
        unsigned ub = (unsigned)__builtin_amdgcn_readfirstlane((int)__float_as_uint(u));
        int k = (int)((ub >> 23) & 0xffu) - 127;
        kexp += k;
        float pes = ldexpf(pe0, -k);         // runs concurrently with FMA tree below

        // ---- matvec: acc[c] = sum_{c'} u[c'] * W[c'][c], broadcast via readlane→SGPR ----
        float a0 = 0.f, a1 = 0.f, a2 = 0.f, a3 = 0.f;
        #pragma unroll
        for (int i = 0; i < 52; i += 4) {
            a0 = fmaf(bcast_lane(u, i + 0), w[i + 0], a0);
            a1 = fmaf(bcast_lane(u, i + 1), w[i + 1], a1);
            a2 = fmaf(bcast_lane(u, i + 2), w[i + 2], a2);
            a3 = fmaf(bcast_lane(u, i + 3), w[i + 3], a3);
        }
        a0 = fmaf(bcast_lane(u, 52), w[52], a0);
        float acc = (a0 + a1) + (a2 + a3);    // > 0 always

        u = acc * pes;

        // ---- rotate emission-prob pipeline (load t+3, clamped in-bounds) ----
        pe0 = pe1; pe1 = pe2;
        int tn = t + 3; if (tn > TT - 1) tn = TT - 1;
        pe2 = __expf(ep[(size_t)tn * CC + cc]);
    }

    // ---- partition = log(sum_c u[c]*exp(T[c,EOS])) + kexp*ln2 ----
    float v = (lane < CC) ? u * __expf(trans[cc * CC + EOS]) : 0.f;
    #pragma unroll
    for (int o = 32; o > 0; o >>= 1) v += __shfl_xor(v, o);
    float logZ = __logf(v) + (float)kexp * 0.6931471805599453f;

    if (lane == 0) partial[b] = logZ - sc;
}

__global__ __launch_bounds__(256) void crf_reduce_kernel(
    const float* __restrict__ partial, float* __restrict__ out)
{
    float s = 0.f;
    #pragma unroll
    for (int k = 0; k < BB / 256; ++k) s += partial[threadIdx.x + 256 * k];
    #pragma unroll
    for (int o = 32; o > 0; o >>= 1) s += __shfl_xor(s, o);
    __shared__ float wsum[4];
    if ((threadIdx.x & 63) == 0) wsum[threadIdx.x >> 6] = s;
    __syncthreads();
    if (threadIdx.x == 0) out[0] = (wsum[0] + wsum[1]) + (wsum[2] + wsum[3]);
}

extern "C" void kernel_launch(void* const* d_in, const int* in_sizes, int n_in,
                              void* d_out, int out_size, void* d_ws, size_t ws_size,
                              hipStream_t stream) {
    const float* em    = (const float*)d_in[0];
    const int*   tags  = (const int*)d_in[1];
    const float* mask  = (const float*)d_in[2];
    const float* trans = (const float*)d_in[3];
    float* out = (float*)d_out;
    float* partial = (float*)d_ws;   // B floats of scratch

    crf_batch_kernel<<<BB, 64, 0, stream>>>(em, tags, mask, trans, partial);
    crf_reduce_kernel<<<1, 256, 0, stream>>>(partial, out);
}

// Round 3
// 360.412 us; speedup vs baseline: 1.0159x; 1.0159x over previous
//
#include <hip/hip_runtime.h>
#include <math.h>

#define BB 1024
#define TT 512
#define CC 53
#define BOS 1
#define EOS 2

__device__ __forceinline__ float bcast_lane(float x, int l) {
    return __uint_as_float(__builtin_amdgcn_readlane(__float_as_uint(x), l));
}

__global__ __launch_bounds__(64) void crf_batch_kernel(
    const float* __restrict__ em,     // B,T,C
    const int*   __restrict__ tags,   // B,T
    const float* __restrict__ mask,   // B,T
    const float* __restrict__ trans,  // C,C
    float*       __restrict__ partial) // B  (partition - score)
{
    const int b = blockIdx.x;
    const int lane = threadIdx.x;             // 0..63
    const int cc = lane < CC ? lane : CC - 1; // lanes >= C mirror lane 52

    // ---- length = sum(mask[b,:]) (exact: entries are 0.0/1.0) ----
    const float* mrow = mask + (size_t)b * TT;
    float msum = 0.f;
    #pragma unroll
    for (int i = 0; i < TT / 64; ++i) msum += mrow[lane + 64 * i];
    #pragma unroll
    for (int o = 32; o > 0; o >>= 1) msum += __shfl_xor(msum, o);
    const int len = (int)(msum + 0.5f);       // in [256, 511]

    // ---- score (gather part), lane-parallel over t ----
    const int* trow = tags + (size_t)b * TT;
    const float* ep = em + (size_t)b * TT * CC;
    float sc = 0.f;
    for (int t = 2 + lane; t < len; t += 64) {
        int tg = trow[t];
        int tp = trow[t - 1];
        sc += ep[(size_t)t * CC + tg] + trans[tp * CC + tg];
    }
    #pragma unroll
    for (int o = 32; o > 0; o >>= 1) sc += __shfl_xor(sc, o);
    if (lane == 0) {
        int t1 = trow[1];
        sc += trans[BOS * CC + t1] + ep[1 * CC + t1];   // "first"
        int tl = trow[len];
        sc += trans[tl * CC + EOS];                      // "last" (ref: tags[:, len])
    }

    // ---- W column in NAMED registers: w_i = exp(trans[i][cc]) ----
    // (a float w[53] array gets demoted to scratch — VGPR_Count=40 in r1/r2 —
    //  and the 53 per-step scratch reloads were the 75% stall. Named scalars
    //  force VGPR allocation.)
#define WD(i) float w##i = __expf(trans[(i) * CC + cc]);
    WD(0)  WD(1)  WD(2)  WD(3)  WD(4)  WD(5)  WD(6)  WD(7)
    WD(8)  WD(9)  WD(10) WD(11) WD(12) WD(13) WD(14) WD(15)
    WD(16) WD(17) WD(18) WD(19) WD(20) WD(21) WD(22) WD(23)
    WD(24) WD(25) WD(26) WD(27) WD(28) WD(29) WD(30) WD(31)
    WD(32) WD(33) WD(34) WD(35) WD(36) WD(37) WD(38) WD(39)
    WD(40) WD(41) WD(42) WD(43) WD(44) WD(45) WD(46) WD(47)
    WD(48) WD(49) WD(50) WD(51) WD(52)
#undef WD

    // ---- linear-domain forward: u = exp(alpha) * 2^-kexp ----
    float u = __expf(trans[BOS * CC + cc] + ep[1 * CC + cc]);
    int kexp = 0;

    // 3-deep prefetch of pe[t] = exp(em[t, cc])
    const float* epc = ep + cc;
    float pe0 = __expf(epc[2 * CC]);
    float pe1 = __expf(epc[3 * CC]);
    float pe2 = __expf(epc[4 * CC]);

#define F4(i0, i1, i2, i3)                         \
    a0 = fmaf(bcast_lane(u, i0), w##i0, a0);       \
    a1 = fmaf(bcast_lane(u, i1), w##i1, a1);       \
    a2 = fmaf(bcast_lane(u, i2), w##i2, a2);       \
    a3 = fmaf(bcast_lane(u, i3), w##i3, a3);

    for (int t = 2; t < len; ++t) {
        // off-critical-path renorm: k = exponent of u[lane0], folded into pe
        unsigned ub = (unsigned)__builtin_amdgcn_readfirstlane((int)__float_as_uint(u));
        int k = (int)((ub >> 23) & 0xffu) - 127;
        kexp += k;
        float pes = ldexpf(pe0, -k);

        float a0 = 0.f, a1 = 0.f, a2 = 0.f, a3 = 0.f;
        F4(0, 1, 2, 3)    F4(4, 5, 6, 7)    F4(8, 9, 10, 11)
        F4(12, 13, 14, 15) F4(16, 17, 18, 19) F4(20, 21, 22, 23)
        F4(24, 25, 26, 27) F4(28, 29, 30, 31) F4(32, 33, 34, 35)
        F4(36, 37, 38, 39) F4(40, 41, 42, 43) F4(44, 45, 46, 47)
        F4(48, 49, 50, 51)
        a0 = fmaf(bcast_lane(u, 52), w52, a0);
        float acc = (a0 + a1) + (a2 + a3);    // > 0 always

        u = acc * pes;

        // rotate emission-prob pipeline (load t+3, clamped in-bounds)
        pe0 = pe1; pe1 = pe2;
        int tn = t + 3; tn = tn > TT - 1 ? TT - 1 : tn;
        pe2 = __expf(epc[(size_t)tn * CC]);
    }
#undef F4

    // ---- partition = log(sum_c u[c]*exp(T[c,EOS])) + kexp*ln2 ----
    float v = (lane < CC) ? u * __expf(trans[cc * CC + EOS]) : 0.f;
    #pragma unroll
    for (int o = 32; o > 0; o >>= 1) v += __shfl_xor(v, o);
    float logZ = __logf(v) + (float)kexp * 0.6931471805599453f;

    if (lane == 0) partial[b] = logZ - sc;
}

__global__ __launch_bounds__(256) void crf_reduce_kernel(
    const float* __restrict__ partial, float* __restrict__ out)
{
    float s = 0.f;
    #pragma unroll
    for (int k = 0; k < BB / 256; ++k) s += partial[threadIdx.x + 256 * k];
    #pragma unroll
    for (int o = 32; o > 0; o >>= 1) s += __shfl_xor(s, o);
    __shared__ float wsum[4];
    if ((threadIdx.x & 63) == 0) wsum[threadIdx.x >> 6] = s;
    __syncthreads();
    if (threadIdx.x == 0) out[0] = (wsum[0] + wsum[1]) + (wsum[2] + wsum[3]);
}

extern "C" void kernel_launch(void* const* d_in, const int* in_sizes, int n_in,
                              void* d_out, int out_size, void* d_ws, size_t ws_size,
                              hipStream_t stream) {
    const float* em    = (const float*)d_in[0];
    const int*   tags  = (const int*)d_in[1];
    const float* mask  = (const float*)d_in[2];
    const float* trans = (const float*)d_in[3];
    float* out = (float*)d_out;
    float* partial = (float*)d_ws;   // B floats of scratch

    crf_batch_kernel<<<BB, 64, 0, stream>>>(em, tags, mask, trans, partial);
    crf_reduce_kernel<<<1, 256, 0, stream>>>(partial, out);
}

// Round 4
// 359.968 us; speedup vs baseline: 1.0172x; 1.0012x over previous
//
#include <hip/hip_runtime.h>
#include <math.h>

#define BB 1024
#define TT 512
#define CC 53
#define BOS 1
#define EOS 2

__device__ __forceinline__ float bcast_lane(float x, int l) {
    return __uint_as_float(__builtin_amdgcn_readlane(__float_as_uint(x), l));
}

// __launch_bounds__(64, 1): second arg = MIN WAVES PER EU = 1. Without it the
// backend budgets VGPRs for 8 waves/SIMD (~64 regs) and spills all 53 w's to
// scratch (observed VGPR_Count=40 in r1-r3, ~840 stall cy/step on reloads).
// We launch 1024 waves = exactly 1/SIMD, so occupancy >1 is worthless here.
__global__ __launch_bounds__(64, 1) void crf_batch_kernel(
    const float* __restrict__ em,     // B,T,C
    const int*   __restrict__ tags,   // B,T
    const float* __restrict__ mask,   // B,T
    const float* __restrict__ trans,  // C,C
    float*       __restrict__ partial) // B  (partition - score)
{
    const int b = blockIdx.x;
    const int lane = threadIdx.x;             // 0..63
    const int cc = lane < CC ? lane : CC - 1; // lanes >= C mirror lane 52

    // ---- length = sum(mask[b,:]) (exact: entries are 0.0/1.0) ----
    const float* mrow = mask + (size_t)b * TT;
    float msum = 0.f;
    #pragma unroll
    for (int i = 0; i < TT / 64; ++i) msum += mrow[lane + 64 * i];
    #pragma unroll
    for (int o = 32; o > 0; o >>= 1) msum += __shfl_xor(msum, o);
    const int len = (int)(msum + 0.5f);       // in [256, 511]

    // ---- score (gather part), lane-parallel over t ----
    const int* trow = tags + (size_t)b * TT;
    const float* ep = em + (size_t)b * TT * CC;
    float sc = 0.f;
    for (int t = 2 + lane; t < len; t += 64) {
        int tg = trow[t];
        int tp = trow[t - 1];
        sc += ep[(size_t)t * CC + tg] + trans[tp * CC + tg];
    }
    #pragma unroll
    for (int o = 32; o > 0; o >>= 1) sc += __shfl_xor(sc, o);
    if (lane == 0) {
        int t1 = trow[1];
        sc += trans[BOS * CC + t1] + ep[1 * CC + t1];   // "first"
        int tl = trow[len];
        sc += trans[tl * CC + EOS];                      // "last" (ref: tags[:, len])
    }

    // ---- W column in NAMED registers: w_i = exp(trans[i][cc]) ----
#define WD(i) float w##i = __expf(trans[(i) * CC + cc]);
    WD(0)  WD(1)  WD(2)  WD(3)  WD(4)  WD(5)  WD(6)  WD(7)
    WD(8)  WD(9)  WD(10) WD(11) WD(12) WD(13) WD(14) WD(15)
    WD(16) WD(17) WD(18) WD(19) WD(20) WD(21) WD(22) WD(23)
    WD(24) WD(25) WD(26) WD(27) WD(28) WD(29) WD(30) WD(31)
    WD(32) WD(33) WD(34) WD(35) WD(36) WD(37) WD(38) WD(39)
    WD(40) WD(41) WD(42) WD(43) WD(44) WD(45) WD(46) WD(47)
    WD(48) WD(49) WD(50) WD(51) WD(52)
#undef WD

    // ---- linear-domain forward: u = exp(alpha) * 2^-kexp ----
    float u = __expf(trans[BOS * CC + cc] + ep[1 * CC + cc]);
    int kexp = 0;

    // 3-deep prefetch of pe[t] = exp(em[t, cc])
    const float* epc = ep + cc;
    float pe0 = __expf(epc[2 * CC]);
    float pe1 = __expf(epc[3 * CC]);
    float pe2 = __expf(epc[4 * CC]);

#define F4(i0, i1, i2, i3)                         \
    a0 = fmaf(bcast_lane(u, i0), w##i0, a0);       \
    a1 = fmaf(bcast_lane(u, i1), w##i1, a1);       \
    a2 = fmaf(bcast_lane(u, i2), w##i2, a2);       \
    a3 = fmaf(bcast_lane(u, i3), w##i3, a3);

    for (int t = 2; t < len; ++t) {
        // off-critical-path renorm: k = exponent of u[lane0], folded into pe
        unsigned ub = (unsigned)__builtin_amdgcn_readfirstlane((int)__float_as_uint(u));
        int k = (int)((ub >> 23) & 0xffu) - 127;
        kexp += k;
        float pes = ldexpf(pe0, -k);

        float a0 = 0.f, a1 = 0.f, a2 = 0.f, a3 = 0.f;
        F4(0, 1, 2, 3)    F4(4, 5, 6, 7)    F4(8, 9, 10, 11)
        F4(12, 13, 14, 15) F4(16, 17, 18, 19) F4(20, 21, 22, 23)
        F4(24, 25, 26, 27) F4(28, 29, 30, 31) F4(32, 33, 34, 35)
        F4(36, 37, 38, 39) F4(40, 41, 42, 43) F4(44, 45, 46, 47)
        F4(48, 49, 50, 51)
        a0 = fmaf(bcast_lane(u, 52), w52, a0);
        float acc = (a0 + a1) + (a2 + a3);    // > 0 always

        u = acc * pes;

        // rotate emission-prob pipeline (load t+3, clamped in-bounds)
        pe0 = pe1; pe1 = pe2;
        int tn = t + 3; tn = tn > TT - 1 ? TT - 1 : tn;
        pe2 = __expf(epc[(size_t)tn * CC]);
    }
#undef F4

    // ---- partition = log(sum_c u[c]*exp(T[c,EOS])) + kexp*ln2 ----
    float v = (lane < CC) ? u * __expf(trans[cc * CC + EOS]) : 0.f;
    #pragma unroll
    for (int o = 32; o > 0; o >>= 1) v += __shfl_xor(v, o);
    float logZ = __logf(v) + (float)kexp * 0.6931471805599453f;

    if (lane == 0) partial[b] = logZ - sc;
}

__global__ __launch_bounds__(256) void crf_reduce_kernel(
    const float* __restrict__ partial, float* __restrict__ out)
{
    float s = 0.f;
    #pragma unroll
    for (int k = 0; k < BB / 256; ++k) s += partial[threadIdx.x + 256 * k];
    #pragma unroll
    for (int o = 32; o > 0; o >>= 1) s += __shfl_xor(s, o);
    __shared__ float wsum[4];
    if ((threadIdx.x & 63) == 0) wsum[threadIdx.x >> 6] = s;
    __syncthreads();
    if (threadIdx.x == 0) out[0] = (wsum[0] + wsum[1]) + (wsum[2] + wsum[3]);
}

extern "C" void kernel_launch(void* const* d_in, const int* in_sizes, int n_in,
                              void* d_out, int out_size, void* d_ws, size_t ws_size,
                              hipStream_t stream) {
    const float* em    = (const float*)d_in[0];
    const int*   tags  = (const int*)d_in[1];
    const float* mask  = (const float*)d_in[2];
    const float* trans = (const float*)d_in[3];
    float* out = (float*)d_out;
    float* partial = (float*)d_ws;   // B floats of scratch

    crf_batch_kernel<<<BB, 64, 0, stream>>>(em, tags, mask, trans, partial);
    crf_reduce_kernel<<<1, 256, 0, stream>>>(partial, out);
}